// Round 1
// baseline (217.389 us; speedup 1.0000x reference)
//
#include <hip/hip_runtime.h>
#include <cstdint>

#define E_EXP 8
#define BATCH 8192
#define D0 480
#define D1 512
#define D2 512
#define D3 363
#define KP 512      // padded per-expert K
#define N3PAD 384

typedef _Float16 f16x8 __attribute__((ext_vector_type(8)));
typedef float f32x16 __attribute__((ext_vector_type(16)));
typedef unsigned short u16;

__device__ __forceinline__ u16 f2h(float f) {
    _Float16 h = (_Float16)f;
    return __builtin_bit_cast(u16, h);
}

// async global->LDS, 16B per lane; LDS dest = wave-uniform base + lane*16
__device__ __forceinline__ void async16(const u16* g, u16* s) {
    __builtin_amdgcn_global_load_lds(
        reinterpret_cast<const __attribute__((address_space(1))) void*>(
            reinterpret_cast<uintptr_t>(g)),
        reinterpret_cast<__attribute__((address_space(3))) void*>(
            reinterpret_cast<uintptr_t>(s)),
        16, 0, 0);
}

// W[e][o][i] fp32 -> wf[e][o][0..511] fp16, zero-padded in o (to OUTP) and i (to 512)
__device__ __forceinline__ void pack_seg(const float* __restrict__ src,
                                         u16* __restrict__ dst,
                                         int OUT_src, int OUTP, int IN_src) {
    int total = E_EXP * OUTP * 128;
    int in4 = IN_src >> 2;
    for (int idx = blockIdx.x * blockDim.x + threadIdx.x; idx < total;
         idx += gridDim.x * blockDim.x) {
        int e = idx / (OUTP * 128);
        int r = idx - e * OUTP * 128;
        int o = r >> 7;
        int k4 = r & 127;
        ushort4 w;
        if (o < OUT_src && k4 < in4) {
            const float4 v = *reinterpret_cast<const float4*>(
                src + ((size_t)e * OUT_src + o) * IN_src + (k4 << 2));
            w.x = f2h(v.x); w.y = f2h(v.y); w.z = f2h(v.z); w.w = f2h(v.w);
        } else {
            w.x = 0; w.y = 0; w.z = 0; w.w = 0;
        }
        *reinterpret_cast<ushort4*>(dst + ((size_t)e * OUTP + o) * KP + (k4 << 2)) = w;
    }
}

__global__ void pack_all(const float* __restrict__ W1, const float* __restrict__ W2,
                         const float* __restrict__ W3, u16* __restrict__ wf1,
                         u16* __restrict__ wf2, u16* __restrict__ wf3) {
    pack_seg(W1, wf1, 512, 512, D0);
    pack_seg(W2, wf2, 512, 512, D1);
    pack_seg(W3, wf3, D3, N3PAD, D2);
}

// x (8192x480 fp32) -> xp (8192x512 fp16, zero-padded)
__global__ void pad_x(const float* __restrict__ x, u16* __restrict__ xp) {
    int total = BATCH * 128;
    for (int idx = blockIdx.x * blockDim.x + threadIdx.x; idx < total;
         idx += gridDim.x * blockDim.x) {
        int b = idx >> 7, k4 = idx & 127;
        ushort4 w;
        if (k4 < 120) {
            const float4 v = *reinterpret_cast<const float4*>(
                x + (size_t)b * D0 + (k4 << 2));
            w.x = f2h(v.x); w.y = f2h(v.y); w.z = f2h(v.z); w.w = f2h(v.w);
        } else {
            w.x = 0; w.y = 0; w.z = 0; w.w = 0;
        }
        *reinterpret_cast<ushort4*>(xp + (size_t)b * KP + (k4 << 2)) = w;
    }
}

// All-expert fused blended GEMM, DOUBLE-BUFFERED (BK=32, 16 passes), 32x32x16 MFMA:
//   acc[m][n] = sum_e bl[e,m] * (A @ W_e^T)[m,n]   (in-register blend on A)
// Tile 256x64; 8 waves = 4m x 2n, wave tile 64x32 (2 m-groups of 32 x 1 n-group).
// acc split by k-half -> 4 independent MFMA chains/wave.
// LDS swizzle: phys_slot = k_slot ^ ((row>>1)&3)  (16 rows -> each bank-quad
// exactly 2x = free 2-way; the old (row&3) key gave 4-way conflicts).
// Grid 32*nbn, 1 block/CU, XCD key on bm.
__global__ __launch_bounds__(512, 2) void gemm_all(
    const u16* __restrict__ A, const u16* __restrict__ Bw,
    const float* __restrict__ blend, const float* __restrict__ bias,
    u16* __restrict__ out, int OUTP, int OUTR, int nbn, int mode) {
    __shared__ __align__(16) u16 S[49152];  // 96 KB = 2 x (As 8192 + Bs 16384)
    const int tid = threadIdx.x;
    const int w = tid >> 6, lane = tid & 63;
    const int wm2 = w & 3, wn2 = w >> 2;
    const int l31 = lane & 31, q2 = lane >> 5;

    const int id = blockIdx.x;
    const int xcd = id & 7;
    const int j = id >> 3;
    const int bm = ((j & 3) << 3) + xcd;  // 0..31 (256-row tiles), pinned to XCD
    const int bn = j >> 2;                // 0..nbn-1

    f32x16 acc[2][2];  // [m-group][k-half]
#pragma unroll
    for (int mg = 0; mg < 2; ++mg)
#pragma unroll
        for (int kk = 0; kk < 2; ++kk)
#pragma unroll
            for (int i = 0; i < 16; ++i) acc[mg][kk][i] = 0.f;

    // per-lane blend scalars: row of A-fragment = lane&31 within 32-row m-group
    _Float16 blh[8][2];
#pragma unroll
    for (int e = 0; e < 8; ++e)
#pragma unroll
        for (int mg = 0; mg < 2; ++mg)
            blh[e][mg] = (_Float16)blend[e * BATCH + bm * 256 + wm2 * 64 +
                                         mg * 32 + l31];

    // staging geometry: 1KB chunk = 16 rows x 32k; lane = r*4 + s
    const int l4r = lane >> 2;                        // row in chunk
    const int l4s = lane & 3;                         // phys 16B slot
    const int ks8 = (l4s ^ ((l4r >> 1) & 3)) << 3;    // swizzled k elem offset
    const size_t EST = (size_t)OUTP * KP;             // expert stride in Bw
    const u16* gA0 = A + (size_t)(bm * 256 + w * 32 + l4r) * KP + ks8;
    const u16* gB0 = Bw + (size_t)w * EST + (size_t)(bn * 64 + l4r) * KP + ks8;
    const size_t R16 = (size_t)16 * KP;
    const int aBase = w * 1024;                // As dst (elems, within buffer)
    const int bBase = 8192 + w * 2048;         // Bs dst (wave w stages expert w)

    // fragment read offsets (loop-invariant); logical k-slot = kk*2 + q2
    int aoff[2][2], boff[2];
#pragma unroll
    for (int mg = 0; mg < 2; ++mg) {
        int r = wm2 * 64 + mg * 32 + l31;
        int base = (r >> 4) * 512 + (r & 15) * 32;
        int swz = (r >> 1) & 3;
#pragma unroll
        for (int kk = 0; kk < 2; ++kk)
            aoff[mg][kk] = base + (((kk * 2 + q2) ^ swz) << 3);
    }
    {
        int r = wn2 * 32 + l31;
        int base = (r >> 4) * 512 + (r & 15) * 32;
        int swz = (r >> 1) & 3;
#pragma unroll
        for (int kk = 0; kk < 2; ++kk)
            boff[kk] = base + (((kk * 2 + q2) ^ swz) << 3);
    }

    auto stage = [&](int kt, int p) {
        const int ko = kt << 5;
        u16* buf = S + p * 24576;
        async16(gA0 + ko, buf + aBase);
        async16(gA0 + R16 + ko, buf + aBase + 512);
        async16(gB0 + ko, buf + bBase);
        async16(gB0 + R16 + ko, buf + bBase + 512);
        async16(gB0 + 2 * R16 + ko, buf + bBase + 1024);
        async16(gB0 + 3 * R16 + ko, buf + bBase + 1536);
    };

    stage(0, 0);
    __syncthreads();

#pragma unroll 2
    for (int kt = 0; kt < 16; ++kt) {
        const int p = kt & 1;
        if (kt < 15) stage(kt + 1, p ^ 1);
        const u16* As_ = S + p * 24576;
        const u16* Bs_ = As_ + 8192;
        f16x8 af[2][2];
#pragma unroll
        for (int mg = 0; mg < 2; ++mg)
#pragma unroll
            for (int kk = 0; kk < 2; ++kk)
                af[mg][kk] = *reinterpret_cast<const f16x8*>(&As_[aoff[mg][kk]]);
#pragma unroll
        for (int e = 0; e < 8; ++e) {
            f16x8 bf0 = *reinterpret_cast<const f16x8*>(&Bs_[e * 2048 + boff[0]]);
            f16x8 bf1 = *reinterpret_cast<const f16x8*>(&Bs_[e * 2048 + boff[1]]);
#pragma unroll
            for (int mg = 0; mg < 2; ++mg) {
                f16x8 a0 = af[mg][0] * blh[e][mg];
                acc[mg][0] = __builtin_amdgcn_mfma_f32_32x32x16_f16(
                    a0, bf0, acc[mg][0], 0, 0, 0);
                f16x8 a1 = af[mg][1] * blh[e][mg];
                acc[mg][1] = __builtin_amdgcn_mfma_f32_32x32x16_f16(
                    a1, bf1, acc[mg][1], 0, 0, 0);
            }
        }
        __syncthreads();
    }

    // fused epilogue: blended bias from LDS tiles (stride 9 = conflict-free),
    // optional ELU, fp16 store. C layout: col=lane&31, row=(reg&3)+8*(reg>>2)+4*q2.
    float* Blf = reinterpret_cast<float*>(S);         // [256][9]
    float* Bif = reinterpret_cast<float*>(S + 8192);  // [64][9] (byte 16384)
    for (int idx = tid; idx < 2048; idx += 512) {
        int e = idx >> 8, r = idx & 255;
        Blf[r * 9 + e] = blend[e * BATCH + bm * 256 + r];
    }
    {
        int e = tid >> 6, c = tid & 63;
        int cg = bn * 64 + c;
        Bif[c * 9 + e] = (cg < OUTR) ? bias[e * OUTR + cg] : 0.f;
    }
    __syncthreads();

    const int col_l = wn2 * 32 + l31;
    const int gcol = bn * 64 + col_l;
    float bif[8];
#pragma unroll
    for (int e = 0; e < 8; ++e) bif[e] = Bif[col_l * 9 + e];
#pragma unroll
    for (int mg = 0; mg < 2; ++mg) {
#pragma unroll
        for (int reg = 0; reg < 16; ++reg) {
            int rloc = (reg & 3) + ((reg >> 2) << 3) + (q2 << 2);
            int rl = wm2 * 64 + mg * 32 + rloc;
            float bb = 0.f;
#pragma unroll
            for (int e = 0; e < 8; ++e) bb += Blf[rl * 9 + e] * bif[e];
            float v = acc[mg][0][reg] + acc[mg][1][reg] + bb;
            if (mode == 0) v = v > 0.f ? v : expm1f(v);
            out[(size_t)(bm * 256 + rl) * OUTP + gcol] = f2h(v);
        }
    }
}

// softmax over D3=363 of fp16 logits (bias already applied) -> fp32 out.
__global__ __launch_bounds__(128) void softmax_rows(
    const u16* __restrict__ P, float* __restrict__ out) {
    const int b = blockIdx.x;
    const int tid = threadIdx.x, lane = tid & 63, w = tid >> 6;
    float v[3];
    int n = 0;
    float mx = -3.4e38f;
    for (int i = tid; i < D3; i += 128) {
        float s = (float)*reinterpret_cast<const _Float16*>(
            P + (size_t)b * N3PAD + i);
        v[n] = s; mx = fmaxf(mx, s); ++n;
    }
#pragma unroll
    for (int off = 32; off >= 1; off >>= 1) mx = fmaxf(mx, __shfl_xor(mx, off, 64));
    __shared__ float sm[4];
    if (lane == 0) sm[w] = mx;
    __syncthreads();
    mx = fmaxf(sm[0], sm[1]);
    float s = 0.f;
    for (int jj = 0; jj < n; ++jj) { v[jj] = expf(v[jj] - mx); s += v[jj]; }
#pragma unroll
    for (int off = 32; off >= 1; off >>= 1) s += __shfl_xor(s, off, 64);
    if (lane == 0) sm[2 + w] = s;
    __syncthreads();
    float inv = 1.f / (sm[2] + sm[3]);
    n = 0;
    for (int i = tid; i < D3; i += 128) { out[(size_t)b * D3 + i] = v[n] * inv; ++n; }
}

extern "C" void kernel_launch(void* const* d_in, const int* in_sizes, int n_in,
                              void* d_out, int out_size, void* d_ws, size_t ws_size,
                              hipStream_t stream) {
    const float* x = (const float*)d_in[0];
    const float* blend = (const float*)d_in[1];
    const float* W1 = (const float*)d_in[2];
    const float* b1 = (const float*)d_in[3];
    const float* W2 = (const float*)d_in[4];
    const float* b2 = (const float*)d_in[5];
    const float* W3 = (const float*)d_in[6];
    const float* b3 = (const float*)d_in[7];
    float* outp = (float*)d_out;

    char* ws = (char*)d_ws;
    u16* wf1 = (u16*)ws; ws += (size_t)E_EXP * 512 * KP * 2;    // 4.19 MB
    u16* wf2 = (u16*)ws; ws += (size_t)E_EXP * 512 * KP * 2;    // 4.19 MB
    u16* wf3 = (u16*)ws; ws += (size_t)E_EXP * N3PAD * KP * 2;  // 3.15 MB
    u16* xp = (u16*)ws;  ws += (size_t)BATCH * KP * 2;          // 8.39 MB
    u16* h1 = (u16*)ws;  ws += (size_t)BATCH * KP * 2;          // 8.39 MB
    u16* h2 = (u16*)ws;  ws += (size_t)BATCH * KP * 2;          // 8.39 MB
    u16* P = (u16*)ws;                                          // 8192*384*2 = 6.29 MB

    pack_all<<<1024, 256, 0, stream>>>(W1, W2, W3, wf1, wf2, wf3);
    pad_x<<<2048, 256, 0, stream>>>(x, xp);

    gemm_all<<<32 * 8, 512, 0, stream>>>(xp, wf1, blend, b1, h1, 512, 512, 8, 0);
    gemm_all<<<32 * 8, 512, 0, stream>>>(h1, wf2, blend, b2, h2, 512, 512, 8, 0);
    gemm_all<<<32 * 6, 512, 0, stream>>>(h2, wf3, blend, b3, P, N3PAD, D3, 6, 1);
    softmax_rows<<<BATCH, 128, 0, stream>>>(P, outp);
}